// Round 5
// baseline (203.010 us; speedup 1.0000x reference)
//
#include <hip/hip_runtime.h>
#include <stdint.h>
#include <stddef.h>

typedef _Float16 h2 __attribute__((ext_vector_type(2)));
typedef _Float16 h8 __attribute__((ext_vector_type(8)));
typedef float f4 __attribute__((ext_vector_type(4)));

union Hfrag { h2 p[4]; h8 v; };

// ---------------- workspace layout (bytes) ----------------
// pmin/pmax (K1 partials, 1 MB) live only K1->K2; xn (written after K2)
// overlays them. Bt + small tables sit above xn. Total ~18.1 MB.
#define WS_XN     0               // f16 [32768][256] = 16,777,216 B
#define WS_PMIN   0               // f32 [512][256] = 512 KB (dead after K2)
#define WS_PMAX   524288          // f32 [512][256] = 512 KB (dead after K2)
#define WS_BT     16777216        // f16 [80 ks][256 col][32 kk] = 1,310,720 B
#define WS_SMALL  (WS_BT + 1310720)
#define WS_MINV   (WS_SMALL + 0)      // f32[256]
#define WS_RANGEV (WS_SMALL + 1024)   // f32[256]
#define WS_SCALEV (WS_SMALL + 2048)   // f32[256]
#define WS_BSC    (WS_SMALL + 3072)
#define WS_BSH    (WS_SMALL + 4096)   // K2 writes partial; K3 block 640 adds bias
#define WS_SSC    (WS_SMALL + 5120)
#define WS_SSH    (WS_SMALL + 6144)

// ---------------- K1: per-feature min/max partials ----------------
__global__ __launch_bounds__(256) void kan_minmax(const float* __restrict__ x,
                                                  float* __restrict__ pmin,
                                                  float* __restrict__ pmax) {
  __shared__ f4 smn[4][64], smx[4][64];
  const int b = blockIdx.x, t = threadIdx.x;
  const int fq = t & 63, rg = t >> 6;
  const float* p = x + (size_t)b * 64 * 256 + (size_t)rg * 16 * 256 + fq * 4;
  f4 mn = (f4)(3.402823466e38f), mx = (f4)(-3.402823466e38f);
#pragma unroll
  for (int j = 0; j < 16; ++j) {
    f4 v = *(const f4*)(p + (size_t)j * 256);
    mn = __builtin_elementwise_min(mn, v);
    mx = __builtin_elementwise_max(mx, v);
  }
  smn[rg][fq] = mn; smx[rg][fq] = mx;
  __syncthreads();
  if (rg == 0) {
#pragma unroll
    for (int g = 1; g < 4; ++g) {
      mn = __builtin_elementwise_min(mn, smn[g][fq]);
      mx = __builtin_elementwise_max(mx, smx[g][fq]);
    }
    *(f4*)(pmin + (size_t)b * 256 + fq * 4) = mn;
    *(f4*)(pmax + (size_t)b * 256 + fq * 4) = mx;
  }
}

// ---------------- K2: finalize minmax + BN constants ----------------
__global__ __launch_bounds__(256) void kan_consts(
    const float* __restrict__ pmin, const float* __restrict__ pmax,
    const float* __restrict__ g1, const float* __restrict__ b1,
    const float* __restrict__ m1, const float* __restrict__ v1,
    const float* __restrict__ g2, const float* __restrict__ b2,
    const float* __restrict__ m2, const float* __restrict__ v2,
    float* __restrict__ minv, float* __restrict__ rangev, float* __restrict__ scalev,
    float* __restrict__ bscv, float* __restrict__ bshv,
    float* __restrict__ sscv, float* __restrict__ sshv) {
  __shared__ float smn[4][64], smx[4][64];
  const int t = threadIdx.x;
  const int ol = t & 63, pg = t >> 6;
  const int o = blockIdx.x * 64 + ol;
  float mn = 3.402823466e38f, mx = -3.402823466e38f;
  for (int p = pg * 128; p < pg * 128 + 128; ++p) {
    mn = fminf(mn, pmin[(size_t)p * 256 + o]);
    mx = fmaxf(mx, pmax[(size_t)p * 256 + o]);
  }
  smn[pg][ol] = mn; smx[pg][ol] = mx;
  __syncthreads();
  if (pg == 0) {
#pragma unroll
    for (int g = 1; g < 4; ++g) {
      mn = fminf(mn, smn[g][ol]);
      mx = fmaxf(mx, smx[g][ol]);
    }
    const float range = mx - mn + 1e-7f;
    minv[o] = mn;
    rangev[o] = range;
    scalev[o] = 1.0f / range;
    const float bs = g1[o] / sqrtf(v1[o] + 1e-3f);
    bscv[o] = bs;
    bshv[o] = b1[o] - m1[o] * bs;          // + bs*min^T Wb added by K3 block 640
    const float ss = g2[o] / sqrtf(v2[o] + 1e-3f);
    sscv[o] = ss;
    sshv[o] = b2[o] - m2[o] * ss;
  }
}

// ---------------- K2b: precompute xn = (x - min)/range as f16 ----------------
// 4096 blocks x 256 threads, 8 elems/thread. Memory-bound (~50 MB).
__global__ __launch_bounds__(256) void kan_xn(
    const float* __restrict__ x, const float* __restrict__ minv,
    const float* __restrict__ scalev, _Float16* __restrict__ xnb) {
  const size_t base = ((size_t)blockIdx.x * 256 + threadIdx.x) * 8;
  const int i = (int)(base & 255);
  f4 a = *(const f4*)(x + base);
  f4 b = *(const f4*)(x + base + 4);
  f4 mn0 = *(const f4*)(minv + i),  mn1 = *(const f4*)(minv + i + 4);
  f4 s0  = *(const f4*)(scalev + i), s1 = *(const f4*)(scalev + i + 4);
  f4 na = (a - mn0) * s0;
  f4 nb = (b - mn1) * s1;
  union { _Float16 h[8]; uint4 u; } pk;
  pk.h[0] = (_Float16)na.x; pk.h[1] = (_Float16)na.y;
  pk.h[2] = (_Float16)na.z; pk.h[3] = (_Float16)na.w;
  pk.h[4] = (_Float16)nb.x; pk.h[5] = (_Float16)nb.y;
  pk.h[6] = (_Float16)nb.z; pk.h[7] = (_Float16)nb.w;
  *(uint4*)(xnb + base) = pk.u;
}

// ---------------- K3: build f16 weight matrix Bt (+ bias fold in block 640) ----------------
// Bt flat index f = (ks*256 + col)*32 + kk   (2B halves), col = half*128+o
// ks<72: spline, knot k = ks>>3, i = (ks&7)*32+kk; val = sw[col,i,k]*ss[col,i]
//        (knot 0 chunks ks 0..7 never read: basis_0 == 0 for xn in [0,1])
// ks>=72: base, i = (ks-72)*32+kk; val = range_i * Wb[i,col]   (A = xn)
// block 640: bshv[o] += bscv[o] * sum_i min_i*Wb[i,o]   (x = xn*range + min fold)
__global__ __launch_bounds__(256) void kan_buildw(
    const float* __restrict__ spline_w, const float* __restrict__ spline_s,
    const float* __restrict__ base_w, const float* __restrict__ rangev,
    const float* __restrict__ minv, const float* __restrict__ bscv,
    float* __restrict__ bshv, _Float16* __restrict__ Bt) {
  if (blockIdx.x == 640) {
    const int o = threadIdx.x;
    float c = 0.0f;
#pragma unroll 4
    for (int i = 0; i < 256; ++i) c = fmaf(minv[i], base_w[(size_t)i * 256 + o], c);
    bshv[o] += bscv[o] * c;
    return;
  }
  const int gid = blockIdx.x * 256 + threadIdx.x;
  const int f = gid * 4;
  const int ks = f >> 13;
  const int col = (f >> 5) & 255;
  const int kk = f & 31;
  float v[4];
  if (ks < 72) {
    const int k = ks >> 3;
    const int i0 = ((ks & 7) << 5) + kk;
#pragma unroll
    for (int j = 0; j < 4; ++j) {
      const int i = i0 + j;
      v[j] = spline_w[(size_t)(col * 256 + i) * 9 + k] * spline_s[col * 256 + i];
    }
  } else {
    const int i0 = (ks - 72) * 32 + kk;
#pragma unroll
    for (int j = 0; j < 4; ++j) {
      const int i = i0 + j;
      v[j] = rangev[i] * base_w[(size_t)i * 256 + col];
    }
  }
  union { _Float16 h[4]; uint2 u; } pk;
#pragma unroll
  for (int j = 0; j < 4; ++j) pk.h[j] = (_Float16)v[j];
  *(uint2*)(Bt + f) = pk.u;
}

// ---------------- K4: fused dual GEMM + BN + SiLU ----------------
// Block = 64 rows x 256 cols; 4 waves n-stacked, each wave 64x64 (m=4, n=4):
// basis-VALU/MFMA = 1.65, B-loads/MFMA = 0.25 (R2's winning ratios), and xn
// is read exactly once across the whole grid. Grid 512 (2 blocks/CU). A comes
// precomputed as f16 xn (no cvt/normalize in the hot loop). No LDS/barriers.
__global__ __launch_bounds__(256, 2) void kan_gemm(
    const _Float16* __restrict__ xnb, const _Float16* __restrict__ Bt,
    const float* __restrict__ bscv, const float* __restrict__ bshv,
    const float* __restrict__ sscv, const float* __restrict__ sshv,
    float* __restrict__ out) {
  const int tid = threadIdx.x;
  const int lane = tid & 63;
  const int wv = tid >> 6;                 // column group 0..3 (64 cols each)
  const int lr = lane & 15, lg = lane >> 4;
  const int mt = blockIdx.x;               // 0..511 (64-row tiles)

  const int rowA = mt * 64 + lr;           // + 16*m
  // B: chunk ks at +ks*16384; lane base covers col = wv*64 + lr, frag n at +n*1024
  const char* btbase = (const char*)Bt + (size_t)(wv * 64 + lr) * 64 + (size_t)lg * 16;

  f4 accS[4][4], accB[4][4];
#pragma unroll
  for (int m = 0; m < 4; ++m)
#pragma unroll
    for (int n = 0; n < 4; ++n) { accS[m][n] = (f4)0.0f; accB[m][n] = (f4)0.0f; }

#pragma unroll 1
  for (int ic = 0; ic < 8; ++ic) {
    const int ib = ic * 32 + lg * 8;
    // A fragments: xn straight from memory (A[m=lane&15][k=(lane>>4)*8+j])
    Hfrag xf[4];
#pragma unroll
    for (int m = 0; m < 4; ++m)
      xf[m].v = *(const h8*)(xnb + (size_t)(rowA + m * 16) * 256 + ib);
#pragma unroll
    for (int it = 0; it < 9; ++it) {   // it 0..7: knots 1..8 ; it 8: base GEMM step
      const int cks = (it < 8) ? ((it + 1) * 8 + ic) : (72 + ic);
      const char* bp = btbase + (size_t)cks * 16384;
      Hfrag bf[4];
#pragma unroll
      for (int n = 0; n < 4; ++n)
        bf[n].v = *(const h8*)(bp + n * 1024);
      if (it < 8) {
        // knot j=it+1 at t=-1+j/4: basis = max(0, min(j/4 - xn, (2-j/4) + xn))
        const float tj = 0.25f * (float)(it + 1);
        const _Float16 c1 = (_Float16)tj;
        const _Float16 c2 = (_Float16)(2.0f - tj);
        h2 hc1; hc1[0] = c1; hc1[1] = c1;
        h2 hc2; hc2[0] = c2; hc2[1] = c2;
        h2 hz;  hz[0] = (_Float16)0.0f; hz[1] = (_Float16)0.0f;
        Hfrag af[4];
#pragma unroll
        for (int m = 0; m < 4; ++m) {
#pragma unroll
          for (int q = 0; q < 4; ++q) {
            h2 xv = xf[m].p[q];
            h2 u = hc1 - xv;
            h2 w = hc2 + xv;
            af[m].p[q] = __builtin_elementwise_max(__builtin_elementwise_min(u, w), hz);
          }
        }
#pragma unroll
        for (int m = 0; m < 4; ++m)
#pragma unroll
          for (int n = 0; n < 4; ++n)
            accS[m][n] = __builtin_amdgcn_mfma_f32_16x16x32_f16(af[m].v, bf[n].v, accS[m][n], 0, 0, 0);
      } else {
        // base step: A = xn directly (range/min folded into B and bias)
#pragma unroll
        for (int m = 0; m < 4; ++m)
#pragma unroll
          for (int n = 0; n < 4; ++n)
            accB[m][n] = __builtin_amdgcn_mfma_f32_16x16x32_f16(xf[m].v, bf[n].v, accB[m][n], 0, 0, 0);
      }
    }
  }

  // epilogue: out = silu(accB*bs + bsh) + accS*ss + ssh   (C layout: col=l&15, row=(l>>4)*4+r)
#pragma unroll
  for (int n = 0; n < 4; ++n) {
    const int col = wv * 64 + n * 16 + lr;
    const float vbs = bscv[col], vbh = bshv[col];
    const float vss = sscv[col], vsh = sshv[col];
#pragma unroll
    for (int m = 0; m < 4; ++m) {
      const int row0 = mt * 64 + m * 16 + lg * 4;
#pragma unroll
      for (int r = 0; r < 4; ++r) {
        const float zb = accB[m][n][r] * vbs + vbh;
        const float si = zb / (1.0f + __expf(-zb));
        const float val = si + accS[m][n][r] * vss + vsh;
        out[(size_t)(row0 + r) * 256 + col] = val;
      }
    }
  }
}

extern "C" void kernel_launch(void* const* d_in, const int* in_sizes, int n_in,
                              void* d_out, int out_size, void* d_ws, size_t ws_size,
                              hipStream_t stream) {
  const float* x        = (const float*)d_in[0];
  const float* base_w   = (const float*)d_in[1];
  const float* spline_w = (const float*)d_in[2];
  const float* spline_s = (const float*)d_in[3];
  const float* g1 = (const float*)d_in[4];
  const float* b1 = (const float*)d_in[5];
  const float* m1 = (const float*)d_in[6];
  const float* v1 = (const float*)d_in[7];
  const float* g2 = (const float*)d_in[8];
  const float* b2 = (const float*)d_in[9];
  const float* m2 = (const float*)d_in[10];
  const float* v2 = (const float*)d_in[11];
  float* out = (float*)d_out;
  char* ws = (char*)d_ws;

  _Float16* xnb = (_Float16*)(ws + WS_XN);
  float* pmin   = (float*)(ws + WS_PMIN);
  float* pmax   = (float*)(ws + WS_PMAX);
  _Float16* Bt  = (_Float16*)(ws + WS_BT);
  float* minv   = (float*)(ws + WS_MINV);
  float* rangev = (float*)(ws + WS_RANGEV);
  float* scalev = (float*)(ws + WS_SCALEV);
  float* bscv   = (float*)(ws + WS_BSC);
  float* bshv   = (float*)(ws + WS_BSH);
  float* sscv   = (float*)(ws + WS_SSC);
  float* sshv   = (float*)(ws + WS_SSH);

  kan_minmax<<<512, 256, 0, stream>>>(x, pmin, pmax);
  kan_consts<<<4, 256, 0, stream>>>(pmin, pmax, g1, b1, m1, v1, g2, b2, m2, v2,
                                    minv, rangev, scalev, bscv, bshv, sscv, sshv);
  kan_xn<<<4096, 256, 0, stream>>>(x, minv, scalev, xnb);
  kan_buildw<<<641, 256, 0, stream>>>(spline_w, spline_s, base_w, rangev,
                                      minv, bscv, bshv, Bt);
  kan_gemm<<<512, 256, 0, stream>>>(xnb, Bt, bscv, bshv, sscv, sshv, out);
}

// Round 7
// 199.569 us; speedup vs baseline: 1.0172x; 1.0172x over previous
//
#include <hip/hip_runtime.h>
#include <stdint.h>
#include <stddef.h>

typedef _Float16 h2 __attribute__((ext_vector_type(2)));
typedef _Float16 h8 __attribute__((ext_vector_type(8)));
typedef float f4 __attribute__((ext_vector_type(4)));

union Hfrag { h2 p[4]; h8 v; };

// ---------------- workspace layout (bytes) ----------------
// pmin/pmax (K1 partials) die after K2; baseh (written by K4b) overlays them.
#define WS_BASEH  0               // f16 [32768][256] = 16,777,216 B
#define WS_PMIN   0               // f32 [512][256] = 512 KB (dead after K2)
#define WS_PMAX   524288          // f32 [512][256] = 512 KB (dead after K2)
#define WS_BT     16777216        // f16 [80 ks][256 col][32 kk] = 1,310,720 B
#define WS_SMALL  (WS_BT + 1310720)
#define WS_BSC    (WS_SMALL + 0)
#define WS_BSH    (WS_SMALL + 1024)
#define WS_SSC    (WS_SMALL + 2048)
#define WS_SSH    (WS_SMALL + 3072)
#define WS_SCH    (WS_SMALL + 4096)   // f16[256]  1/range
#define WS_MSCH   (WS_SMALL + 4608)   // f16[256]  min/range

// ---------------- K1: per-feature min/max partials ----------------
__global__ __launch_bounds__(256) void kan_minmax(const float* __restrict__ x,
                                                  float* __restrict__ pmin,
                                                  float* __restrict__ pmax) {
  __shared__ f4 smn[4][64], smx[4][64];
  const int b = blockIdx.x, t = threadIdx.x;
  const int fq = t & 63, rg = t >> 6;
  const float* p = x + (size_t)b * 64 * 256 + (size_t)rg * 16 * 256 + fq * 4;
  f4 mn = (f4)(3.402823466e38f), mx = (f4)(-3.402823466e38f);
#pragma unroll
  for (int j = 0; j < 16; ++j) {
    f4 v = *(const f4*)(p + (size_t)j * 256);
    mn = __builtin_elementwise_min(mn, v);
    mx = __builtin_elementwise_max(mx, v);
  }
  smn[rg][fq] = mn; smx[rg][fq] = mx;
  __syncthreads();
  if (rg == 0) {
#pragma unroll
    for (int g = 1; g < 4; ++g) {
      mn = __builtin_elementwise_min(mn, smn[g][fq]);
      mx = __builtin_elementwise_max(mx, smx[g][fq]);
    }
    *(f4*)(pmin + (size_t)b * 256 + fq * 4) = mn;
    *(f4*)(pmax + (size_t)b * 256 + fq * 4) = mx;
  }
}

// ---------------- K2: finalize minmax + BN constants + f16 tables ----------------
__global__ __launch_bounds__(256) void kan_consts(
    const float* __restrict__ pmin, const float* __restrict__ pmax,
    const float* __restrict__ g1, const float* __restrict__ b1,
    const float* __restrict__ m1, const float* __restrict__ v1,
    const float* __restrict__ g2, const float* __restrict__ b2,
    const float* __restrict__ m2, const float* __restrict__ v2,
    float* __restrict__ bscv, float* __restrict__ bshv,
    float* __restrict__ sscv, float* __restrict__ sshv,
    _Float16* __restrict__ sch, _Float16* __restrict__ msch) {
  __shared__ float smn[4][64], smx[4][64];
  const int t = threadIdx.x;
  const int ol = t & 63, pg = t >> 6;
  const int o = blockIdx.x * 64 + ol;
  float mn = 3.402823466e38f, mx = -3.402823466e38f;
  for (int p = pg * 128; p < pg * 128 + 128; ++p) {
    mn = fminf(mn, pmin[(size_t)p * 256 + o]);
    mx = fmaxf(mx, pmax[(size_t)p * 256 + o]);
  }
  smn[pg][ol] = mn; smx[pg][ol] = mx;
  __syncthreads();
  if (pg == 0) {
#pragma unroll
    for (int g = 1; g < 4; ++g) {
      mn = fminf(mn, smn[g][ol]);
      mx = fmaxf(mx, smx[g][ol]);
    }
    const float range = mx - mn + 1e-7f;
    const float sc = 1.0f / range;
    sch[o]  = (_Float16)sc;
    msch[o] = (_Float16)(mn * sc);
    const float bs = g1[o] / sqrtf(v1[o] + 1e-3f);
    bscv[o] = bs;
    bshv[o] = b1[o] - m1[o] * bs;          // plain BN shift (no folds)
    const float ss = g2[o] / sqrtf(v2[o] + 1e-3f);
    sscv[o] = ss;
    sshv[o] = b2[o] - m2[o] * ss;
  }
}

// ---------------- K3: build f16 weight matrix Bt ----------------
// Bt flat index f = (ks*256 + col)*32 + kk   (2B halves)
// ks<72: spline, knot k = ks>>3, i = (ks&7)*32+kk; val = sw[col,i,k]*ss[col,i]
//        (knot 0 chunks ks 0..7 never read: basis_0 == 0 for xn in [0,1])
// ks>=72: base, i = (ks-72)*32+kk; val = Wb[i,col]   (A = f16(x), no folds)
__global__ __launch_bounds__(256) void kan_buildw(
    const float* __restrict__ spline_w, const float* __restrict__ spline_s,
    const float* __restrict__ base_w, _Float16* __restrict__ Bt) {
  const int gid = blockIdx.x * 256 + threadIdx.x;  // 640 blocks
  const int f = gid * 4;
  const int ks = f >> 13;
  const int col = (f >> 5) & 255;
  const int kk = f & 31;
  float v[4];
  if (ks < 72) {
    const int k = ks >> 3;
    const int i0 = ((ks & 7) << 5) + kk;
#pragma unroll
    for (int j = 0; j < 4; ++j) {
      const int i = i0 + j;
      v[j] = spline_w[(size_t)(col * 256 + i) * 9 + k] * spline_s[col * 256 + i];
    }
  } else {
    const int i0 = (ks - 72) * 32 + kk;
#pragma unroll
    for (int j = 0; j < 4; ++j) {
      const int i = i0 + j;
      v[j] = base_w[(size_t)i * 256 + col];
    }
  }
  union { _Float16 h[4]; uint2 u; } pk;
#pragma unroll
  for (int j = 0; j < 4; ++j) pk.h[j] = (_Float16)v[j];
  *(uint2*)(Bt + f) = pk.u;
}

// ---------------- K4b: base GEMM -> BN -> SiLU -> baseh (f16) ----------------
// R2-proven scheme: A = f16(x), B = plain Wb (Bt ks 72..79). Single acc
// (64 regs). Block 128x128 (2x2 waves of 64x64, m=4,n=4), grid 512.
__global__ __launch_bounds__(256, 2) void kan_base(
    const float* __restrict__ x, const _Float16* __restrict__ Bt,
    const float* __restrict__ bscv, const float* __restrict__ bshv,
    _Float16* __restrict__ baseh) {
  const int tid = threadIdx.x;
  const int lane = tid & 63;
  const int wv = tid >> 6;
  const int wm = wv >> 1, wn = wv & 1;
  const int lr = lane & 15, lg = lane >> 4;
  const int mt = blockIdx.x >> 1, ct = blockIdx.x & 1;

  const int rowA = mt * 128 + wm * 64 + lr;          // + 16*m
  const int colB = ct * 128 + wn * 64 + lr;          // + 16*n

  f4 acc[4][4];
#pragma unroll
  for (int m = 0; m < 4; ++m)
#pragma unroll
    for (int n = 0; n < 4; ++n) acc[m][n] = (f4)0.0f;

  const char* btbase = (const char*)Bt + (size_t)72 * 16384 + (size_t)colB * 64 + (size_t)lg * 16;

#pragma unroll 1
  for (int kc = 0; kc < 8; ++kc) {
    const int ib = kc * 32 + lg * 8;
    Hfrag af[4];
#pragma unroll
    for (int m = 0; m < 4; ++m) {
      const float* px = x + (size_t)(rowA + m * 16) * 256 + ib;
      f4 a = *(const f4*)px;
      f4 b = *(const f4*)(px + 4);
      af[m].p[0][0] = (_Float16)a.x; af[m].p[0][1] = (_Float16)a.y;
      af[m].p[1][0] = (_Float16)a.z; af[m].p[1][1] = (_Float16)a.w;
      af[m].p[2][0] = (_Float16)b.x; af[m].p[2][1] = (_Float16)b.y;
      af[m].p[3][0] = (_Float16)b.z; af[m].p[3][1] = (_Float16)b.w;
    }
    const char* bp = btbase + (size_t)kc * 16384;
    Hfrag bf[4];
#pragma unroll
    for (int n = 0; n < 4; ++n)
      bf[n].v = *(const h8*)(bp + n * 1024);
#pragma unroll
    for (int m = 0; m < 4; ++m)
#pragma unroll
      for (int n = 0; n < 4; ++n)
        acc[m][n] = __builtin_amdgcn_mfma_f32_16x16x32_f16(af[m].v, bf[n].v, acc[m][n], 0, 0, 0);
  }

#pragma unroll
  for (int n = 0; n < 4; ++n) {
    const int col = colB + n * 16;
    const float vbs = bscv[col], vbh = bshv[col];
#pragma unroll
    for (int m = 0; m < 4; ++m) {
      const int row0 = mt * 128 + wm * 64 + m * 16 + lg * 4;
#pragma unroll
      for (int r = 0; r < 4; ++r) {
        const float zb = acc[m][n][r] * vbs + vbh;
        const float si = zb / (1.0f + __expf(-zb));
        baseh[(size_t)(row0 + r) * 256 + col] = (_Float16)si;
      }
    }
  }
}

// ---------------- K4a: spline GEMM (K-split x2) + BN + add baseh ----------------
// Block 64 rows x 128 cols, 4 waves = 2 K-halves x 2 col-halves; wave 64x64
// (m=4,n=4). Single acc (64 regs) -> 3 waves/SIMD. Grid 1024. Partials
// combined via 16 KB LDS pairwise exchange (3 barriers). Basis via builtin
// min/max (R5-proven).
__global__ __launch_bounds__(256, 3) void kan_spline(
    const float* __restrict__ x, const _Float16* __restrict__ Bt,
    const _Float16* __restrict__ sch, const _Float16* __restrict__ msch,
    const float* __restrict__ sscv, const float* __restrict__ sshv,
    const _Float16* __restrict__ baseh, float* __restrict__ out) {
  __shared__ __attribute__((aligned(16))) f4 ex[4][256];   // 16 KB
  const int tid = threadIdx.x;
  const int lane = tid & 63;
  const int wv = tid >> 6;
  const int kh = wv >> 1;                  // K-half
  const int wn = wv & 1;                   // col-half
  const int lr = lane & 15, lg = lane >> 4;
  const int mt = blockIdx.x & 511, ct = blockIdx.x >> 9;  // b, b+512 share XCD -> x reuse

  const int rowA = mt * 64 + lr;           // + 16*m
  const int colB = ct * 128 + wn * 64 + lr;  // + 16*n

  f4 accS[4][4];
#pragma unroll
  for (int m = 0; m < 4; ++m)
#pragma unroll
    for (int n = 0; n < 4; ++n) accS[m][n] = (f4)0.0f;

  const char* btbase = (const char*)Bt + (size_t)colB * 64 + (size_t)lg * 16;

#pragma unroll 1
  for (int icc = 0; icc < 4; ++icc) {
    const int ic = kh * 4 + icc;
    const int ib = ic * 32 + lg * 8;
    Hfrag sc8, ms8;
    sc8.v = *(const h8*)(sch + ib);
    ms8.v = *(const h8*)(msch + ib);
    // xn = f16(x)*sc - min*sc  (pk ops), A-fragment layout
    Hfrag xn[4];
#pragma unroll
    for (int m = 0; m < 4; ++m) {
      const float* px = x + (size_t)(rowA + m * 16) * 256 + ib;
      f4 a = *(const f4*)px;
      f4 b = *(const f4*)(px + 4);
      h2 h0; h0[0] = (_Float16)a.x; h0[1] = (_Float16)a.y;
      h2 h1; h1[0] = (_Float16)a.z; h1[1] = (_Float16)a.w;
      h2 h2v; h2v[0] = (_Float16)b.x; h2v[1] = (_Float16)b.y;
      h2 h3; h3[0] = (_Float16)b.z; h3[1] = (_Float16)b.w;
      xn[m].p[0] = h0 * sc8.p[0] - ms8.p[0];
      xn[m].p[1] = h1 * sc8.p[1] - ms8.p[1];
      xn[m].p[2] = h2v * sc8.p[2] - ms8.p[2];
      xn[m].p[3] = h3 * sc8.p[3] - ms8.p[3];
    }
#pragma unroll
    for (int it = 0; it < 8; ++it) {       // knots 1..8
      const int cks = (it + 1) * 8 + ic;
      const char* bp = btbase + (size_t)cks * 16384;
      Hfrag bf[4];
#pragma unroll
      for (int n = 0; n < 4; ++n)
        bf[n].v = *(const h8*)(bp + n * 1024);
      // knot j=it+1 at t=-1+j/4: basis = max(0, min(j/4 - xn, (2-j/4) + xn))
      const float tj = 0.25f * (float)(it + 1);
      const _Float16 c1 = (_Float16)tj;
      const _Float16 c2 = (_Float16)(2.0f - tj);
      h2 hc1; hc1[0] = c1; hc1[1] = c1;
      h2 hc2; hc2[0] = c2; hc2[1] = c2;
      h2 hz;  hz[0] = (_Float16)0.0f; hz[1] = (_Float16)0.0f;
      Hfrag af[4];
#pragma unroll
      for (int m = 0; m < 4; ++m) {
#pragma unroll
        for (int q = 0; q < 4; ++q) {
          h2 u = hc1 - xn[m].p[q];
          h2 w = hc2 + xn[m].p[q];
          af[m].p[q] = __builtin_elementwise_max(__builtin_elementwise_min(u, w), hz);
        }
      }
#pragma unroll
      for (int m = 0; m < 4; ++m)
#pragma unroll
        for (int n = 0; n < 4; ++n)
          accS[m][n] = __builtin_amdgcn_mfma_f32_16x16x32_f16(af[m].v, bf[n].v, accS[m][n], 0, 0, 0);
    }
  }

  // ---- K-split reduction: pair waves (kh=0,wn) <-> (kh=1,wn); each keeps 2 m's ----
  const int ptid = tid ^ 128;              // partner wave, same lane
#pragma unroll
  for (int r = 0; r < 2; ++r) {
    const int mg = (kh == 0) ? (2 + r) : r;    // give away
    const int mk = (kh == 0) ? r : (2 + r);    // keep & own epilogue
    if (r) __syncthreads();
#pragma unroll
    for (int n = 0; n < 4; ++n) ex[n][tid] = accS[mg][n];
    __syncthreads();
#pragma unroll
    for (int n = 0; n < 4; ++n) accS[mk][n] += ex[n][ptid];
  }

  // epilogue: out = accS*ss + ssh + baseh   (C layout: col=l&15, row=(l>>4)*4+r)
#pragma unroll
  for (int r2 = 0; r2 < 2; ++r2) {
    const int mk = (kh == 0) ? r2 : (2 + r2);
#pragma unroll
    for (int n = 0; n < 4; ++n) {
      const int col = colB + n * 16;
      const float vss = sscv[col], vsh = sshv[col];
      const int row0 = mt * 64 + mk * 16 + lg * 4;
#pragma unroll
      for (int r = 0; r < 4; ++r) {
        const size_t idx = (size_t)(row0 + r) * 256 + col;
        out[idx] = accS[mk][n][r] * vss + vsh + (float)baseh[idx];
      }
    }
  }
}

extern "C" void kernel_launch(void* const* d_in, const int* in_sizes, int n_in,
                              void* d_out, int out_size, void* d_ws, size_t ws_size,
                              hipStream_t stream) {
  const float* x        = (const float*)d_in[0];
  const float* base_w   = (const float*)d_in[1];
  const float* spline_w = (const float*)d_in[2];
  const float* spline_s = (const float*)d_in[3];
  const float* g1 = (const float*)d_in[4];
  const float* b1 = (const float*)d_in[5];
  const float* m1 = (const float*)d_in[6];
  const float* v1 = (const float*)d_in[7];
  const float* g2 = (const float*)d_in[8];
  const float* b2 = (const float*)d_in[9];
  const float* m2 = (const float*)d_in[10];
  const float* v2 = (const float*)d_in[11];
  float* out = (float*)d_out;
  char* ws = (char*)d_ws;

  _Float16* baseh = (_Float16*)(ws + WS_BASEH);
  float* pmin   = (float*)(ws + WS_PMIN);
  float* pmax   = (float*)(ws + WS_PMAX);
  _Float16* Bt  = (_Float16*)(ws + WS_BT);
  float* bscv   = (float*)(ws + WS_BSC);
  float* bshv   = (float*)(ws + WS_BSH);
  float* sscv   = (float*)(ws + WS_SSC);
  float* sshv   = (float*)(ws + WS_SSH);
  _Float16* sch  = (_Float16*)(ws + WS_SCH);
  _Float16* msch = (_Float16*)(ws + WS_MSCH);

  kan_minmax<<<512, 256, 0, stream>>>(x, pmin, pmax);
  kan_consts<<<4, 256, 0, stream>>>(pmin, pmax, g1, b1, m1, v1, g2, b2, m2, v2,
                                    bscv, bshv, sscv, sshv, sch, msch);
  kan_buildw<<<640, 256, 0, stream>>>(spline_w, spline_s, base_w, Bt);
  kan_base<<<512, 256, 0, stream>>>(x, Bt, bscv, bshv, baseh);
  kan_spline<<<1024, 256, 0, stream>>>(x, Bt, sch, msch, sscv, sshv, baseh, out);
}